// Round 3
// baseline (251.186 us; speedup 1.0000x reference)
//
#include <hip/hip_runtime.h>
#include <hip/hip_bf16.h>
#include <stdint.h>

#define T_LEN  2048
#define E_DIM  1024
#define BATCH  4
#define HEADS  16
#define HDIM   64
#define CHUNK_ 128
#define NCHUNK 16
#define EPS_   1e-6f

typedef __attribute__((ext_vector_type(8))) short bf16x8;
typedef __attribute__((ext_vector_type(4))) float f32x4;

__device__ __forceinline__ float b2f(__hip_bfloat16 h) { return __bfloat162float(h); }
__device__ __forceinline__ unsigned short f2bu(float f) {
  __hip_bfloat16 h = __float2bfloat16(f);
  return *(unsigned short*)&h;
}
// async global->LDS, 16B per lane; LDS dest = base + lane*16 (wave-uniform base)
__device__ __forceinline__ void gld_lds16(const void* g, void* l) {
  __builtin_amdgcn_global_load_lds((const __attribute__((address_space(1))) void*)g,
                                   (__attribute__((address_space(3))) void*)l,
                                   16, 0, 0);
}

#define MFMA16(a, b, c) __builtin_amdgcn_mfma_f32_16x16x32_bf16((a), (b), (c), 0, 0, 0)

// ---------------------------------------------------------------------------
// fp32 -> bf16 cast for x (8192x1024) and four 1024x1024 weights.
// ---------------------------------------------------------------------------
__global__ __launch_bounds__(256)
void cast5(const float* __restrict__ x,  const float* __restrict__ w0,
           const float* __restrict__ w1, const float* __restrict__ w2,
           const float* __restrict__ w3,
           __hip_bfloat16* __restrict__ xb,  __hip_bfloat16* __restrict__ w0b,
           __hip_bfloat16* __restrict__ w1b, __hip_bfloat16* __restrict__ w2b,
           __hip_bfloat16* __restrict__ w3b)
{
  const int b = blockIdx.x;
  const float* s;
  __hip_bfloat16* d;
  size_t off;
  if (b < 8192) { s = x; d = xb; off = (size_t)b * 1024; }
  else {
    const int i = (b - 8192) >> 10;
    const int r = (b - 8192) & 1023;
    s = (i == 0) ? w0 : (i == 1) ? w1 : (i == 2) ? w2 : w3;
    d = (i == 0) ? w0b : (i == 1) ? w1b : (i == 2) ? w2b : w3b;
    off = (size_t)r * 1024;
  }
  const int t = threadIdx.x;
  float4 v = *(const float4*)(s + off + (size_t)t * 4);
  ushort4 o;
  o.x = f2bu(v.x); o.y = f2bu(v.y); o.z = f2bu(v.z); o.w = f2bu(v.w);
  *(ushort4*)((unsigned short*)d + off + (size_t)t * 4) = o;
}

// ---------------------------------------------------------------------------
// 128x128 GEMM core (m97 structure) — still used by gemm_out.
// ---------------------------------------------------------------------------
__device__ __forceinline__ void gemm128_core(
    const __hip_bfloat16* __restrict__ X,
    const __hip_bfloat16* __restrict__ W,
    int bm, int bn, f32x4 acc[4][4],
    __hip_bfloat16* Xs, __hip_bfloat16* Ws)
{
  const int t = threadIdx.x, lane = t & 63, wave = t >> 6;
  const int wm = (wave >> 1) * 64, wn = (wave & 1) * 64;
  for (int k0 = 0; k0 < 1024; k0 += 32) {
    if (k0) __syncthreads();
#pragma unroll
    for (int i = 0; i < 2; ++i) {
      const int j = wave * 2 + i;
      const int m = j * 16 + (lane >> 2);
      const int kg = lane & 3;
      gld_lds16(X + (size_t)(bm * 128 + m) * 1024 + k0 + kg * 8, (char*)Xs + j * 1024);
      gld_lds16(W + (size_t)(bn * 128 + m) * 1024 + k0 + kg * 8, (char*)Ws + j * 1024);
    }
    __syncthreads();
    bf16x8 a[4], b[4];
#pragma unroll
    for (int i = 0; i < 4; ++i) {
      a[i] = *(const bf16x8*)&Xs[((wm + i * 16 + (lane & 15)) * 4 + (lane >> 4)) * 8];
      b[i] = *(const bf16x8*)&Ws[((wn + i * 16 + (lane & 15)) * 4 + (lane >> 4)) * 8];
    }
#pragma unroll
    for (int i = 0; i < 4; ++i)
#pragma unroll
      for (int jn = 0; jn < 4; ++jn)
        acc[i][jn] = MFMA16(a[i], b[jn], acc[i][jn]);
  }
}

// ---------------------------------------------------------------------------
// Fused q/k/v projection v3 — 256x256 tile, BK=64, 16 K-steps, dbuf.
// Grid (32, 12) = 384 blocks. 512 threads = 8 waves (2M x 4N); per-wave
// output 128x64 (acc[8][4]) -> 2.67 MFMA per ds_read_b128 (v2's 64x64 had
// 2.0 and was LDS-read-bound: per-CU reads 1540cyc > MFMA 1240cyc).
// LDS: 2 x (A 256x64 + B 256x64) bf16 = 128 KiB.
//
// v2's verified sync skeleton: ONE barrier + ONE vmcnt per K-step, no
// explicit lgkmcnt (compiler emits counted waits per frag). Per step j:
//   p0: read a(half0) 8 + b(half0) 4 | stage A0,A1,B0 of j+1 | 16 MFMA q(0,0)
//   p1: read b(half1) 4              | stage A2,A3,B1        | 16 MFMA q(0,1)
//   p2: read a(half1) 8              | stage B2,B3           | 16 MFMA q(1,0)
//   p3:                                                       16 MFMA q(1,1)
//   vmcnt(0) [j+1's 8 loads, all issued >=2 phases ago] ; barrier
// Granule-XOR swizzle (verified r1/r2, 0 conflicts): logical (row,cg) at
// granule slot cg^(row&7); applied to global SOURCE of global_load_lds and
// to the ds_read address (both-sides involution, rule #21).
// ---------------------------------------------------------------------------
__global__ __launch_bounds__(512, 2)
void gemm_qkv_v3(const __hip_bfloat16* __restrict__ X,
                 const __hip_bfloat16* __restrict__ Wq,
                 const __hip_bfloat16* __restrict__ Wk,
                 const __hip_bfloat16* __restrict__ Wv,
                 __hip_bfloat16* __restrict__ qo,
                 __hip_bfloat16* __restrict__ ko,
                 __hip_bfloat16* __restrict__ vo)
{
  __shared__ __align__(16) unsigned short As[2][16384];   // 2 x 32 KiB
  __shared__ __align__(16) unsigned short Bs[2][16384];   // 2 x 32 KiB

  const int bm = blockIdx.x;            // 0..31 (M tiles of 256)
  const int byy = blockIdx.y;           // 0..11
  const int which = byy >> 2, bn = byy & 3;
  const __hip_bfloat16* Wsel = (which == 0) ? Wq : (which == 1) ? Wk : Wv;
  __hip_bfloat16* Cc = (which == 0) ? qo : (which == 1) ? ko : vo;
  const bool elu = (which < 2);

  const int t = threadIdx.x, lane = t & 63, wv = t >> 6;
  const int wm = (wv >> 2) * 128;       // 0 / 128
  const int wn = (wv & 3) * 64;         // 0 / 64 / 128 / 192

  const __hip_bfloat16* Xp = X + (size_t)(bm * 256) * 1024;
  const __hip_bfloat16* Wp = Wsel + (size_t)(bn * 256) * 1024;

  // ds_read addr (bytes): rowbase*128 + (l&15)*128 + ((ksub*4+(l>>4))^(l&7))*16
  const int lo    = (lane & 15) * 128;
  const int lohi0 = lo + (((lane >> 4)    ) ^ (lane & 7)) * 16;
  const int lohi1 = lo + (((lane >> 4) | 4) ^ (lane & 7)) * 16;
  // stage source: row = row0 + (l>>3), granule cg = (l&7)^(l>>3); dest linear
  const int srow = lane >> 3;
  const int scg  = (lane & 7) ^ (lane >> 3);

  // one gld_lds16 call = 8 wave-instructions; wave wv stages rows row0w..+7
  auto stageA = [&](int buf, int k0, int u) {
    const int row0 = u * 64 + wv * 8;
    gld_lds16(Xp + (size_t)(row0 + srow) * 1024 + k0 + scg * 8,
              (char*)&As[buf][0] + row0 * 128);
  };
  auto stageB = [&](int buf, int k0, int u) {
    const int row0 = u * 64 + wv * 8;
    gld_lds16(Wp + (size_t)(row0 + srow) * 1024 + k0 + scg * 8,
              (char*)&Bs[buf][0] + row0 * 128);
  };
  auto rdA = [&](int buf, int half, bf16x8 (&d)[4][2]) {
#pragma unroll
    for (int m = 0; m < 4; ++m) {
      const int rb = wm + half * 64 + m * 16;
      d[m][0] = *(const bf16x8*)((const char*)&As[buf][0] + rb * 128 + lohi0);
      d[m][1] = *(const bf16x8*)((const char*)&As[buf][0] + rb * 128 + lohi1);
    }
  };
  auto rdB = [&](int buf, int half, bf16x8 (&d)[2][2]) {
#pragma unroll
    for (int n = 0; n < 2; ++n) {
      const int rb = wn + half * 32 + n * 16;
      d[n][0] = *(const bf16x8*)((const char*)&Bs[buf][0] + rb * 128 + lohi0);
      d[n][1] = *(const bf16x8*)((const char*)&Bs[buf][0] + rb * 128 + lohi1);
    }
  };

  f32x4 acc[8][4];
#pragma unroll
  for (int m = 0; m < 8; ++m)
#pragma unroll
    for (int n = 0; n < 4; ++n) acc[m][n] = (f32x4){0.f, 0.f, 0.f, 0.f};

  // ---- prologue: stage step 0 fully; drain; barrier ----
#pragma unroll
  for (int u = 0; u < 4; ++u) stageA(0, 0, u);
#pragma unroll
  for (int u = 0; u < 4; ++u) stageB(0, 0, u);
  asm volatile("s_waitcnt vmcnt(0)" ::: "memory");
  __builtin_amdgcn_s_barrier();
  __builtin_amdgcn_sched_barrier(0);

  auto kstep = [&](int j, int buf, bool dost) {
    const int nbuf = buf ^ 1;
    const int k0n  = (j + 1) * 64;
    bf16x8 a[4][2], b0[2][2], b1[2][2];

    // ---- p0: quad (m-half0, n-half0) ----
    rdA(buf, 0, a); rdB(buf, 0, b0);
    if (dost) { stageA(nbuf, k0n, 0); stageA(nbuf, k0n, 1); stageB(nbuf, k0n, 0); }
    __builtin_amdgcn_s_setprio(1);
#pragma unroll
    for (int m = 0; m < 4; ++m)
#pragma unroll
      for (int n = 0; n < 2; ++n) {
        acc[m][n] = MFMA16(a[m][0], b0[n][0], acc[m][n]);
        acc[m][n] = MFMA16(a[m][1], b0[n][1], acc[m][n]);
      }
    __builtin_amdgcn_s_setprio(0);

    // ---- p1: quad (m-half0, n-half1) ----
    rdB(buf, 1, b1);
    if (dost) { stageA(nbuf, k0n, 2); stageA(nbuf, k0n, 3); stageB(nbuf, k0n, 1); }
    __builtin_amdgcn_s_setprio(1);
#pragma unroll
    for (int m = 0; m < 4; ++m)
#pragma unroll
      for (int n = 0; n < 2; ++n) {
        acc[m][2 + n] = MFMA16(a[m][0], b1[n][0], acc[m][2 + n]);
        acc[m][2 + n] = MFMA16(a[m][1], b1[n][1], acc[m][2 + n]);
      }
    __builtin_amdgcn_s_setprio(0);

    // ---- p2: quad (m-half1, n-half0); a(half0) dead, reuse regs ----
    rdA(buf, 1, a);
    if (dost) { stageB(nbuf, k0n, 2); stageB(nbuf, k0n, 3); }
    __builtin_amdgcn_s_setprio(1);
#pragma unroll
    for (int m = 0; m < 4; ++m)
#pragma unroll
      for (int n = 0; n < 2; ++n) {
        acc[4 + m][n] = MFMA16(a[m][0], b0[n][0], acc[4 + m][n]);
        acc[4 + m][n] = MFMA16(a[m][1], b0[n][1], acc[4 + m][n]);
      }
    __builtin_amdgcn_s_setprio(0);

    // ---- p3: quad (m-half1, n-half1), register-only ----
    __builtin_amdgcn_s_setprio(1);
#pragma unroll
    for (int m = 0; m < 4; ++m)
#pragma unroll
      for (int n = 0; n < 2; ++n) {
        acc[4 + m][2 + n] = MFMA16(a[m][0], b1[n][0], acc[4 + m][2 + n]);
        acc[4 + m][2 + n] = MFMA16(a[m][1], b1[n][1], acc[4 + m][2 + n]);
      }
    __builtin_amdgcn_s_setprio(0);

    if (dost) {
      // j+1's 8 loads: newest issued >=2 phases (~1200cyc) ago
      asm volatile("s_waitcnt vmcnt(0)" ::: "memory");
      __builtin_amdgcn_s_barrier();
      __builtin_amdgcn_sched_barrier(0);
    }
  };

#pragma unroll 1
  for (int jj = 0; jj < 7; ++jj) {
    kstep(2 * jj,     0, true);
    kstep(2 * jj + 1, 1, true);
  }
  kstep(14, 0, true);
  kstep(15, 1, false);

  // ---- epilogue: optional elu(x)+1 and bf16 store ----
  const int lm = lane & 15;
  const int r0 = (lane >> 4) * 4;
#pragma unroll
  for (int m = 0; m < 8; ++m) {
    const int row = bm * 256 + wm + m * 16 + r0;
#pragma unroll
    for (int n = 0; n < 4; ++n) {
      const int col = bn * 256 + wn + n * 16 + lm;
#pragma unroll
      for (int r = 0; r < 4; ++r) {
        float vv = acc[m][n][r];
        if (elu) vv = (vv > 0.f) ? (vv + 1.f) : __expf(vv);
        Cc[(size_t)(row + r) * 1024 + col] = __float2bfloat16(vv);
      }
    }
  }
}

// output projection: fp32 out + bias; grid (64, 8)
__global__ __launch_bounds__(256, 2)
void gemm_out(const __hip_bfloat16* __restrict__ X,
              const __hip_bfloat16* __restrict__ W,
              const float* __restrict__ bias,
              float* __restrict__ C)
{
  __shared__ __align__(16) __hip_bfloat16 Xs[128 * 32];
  __shared__ __align__(16) __hip_bfloat16 Ws[128 * 32];
  const int bm = blockIdx.x, bn = blockIdx.y;
  f32x4 acc[4][4];
#pragma unroll
  for (int i = 0; i < 4; ++i)
#pragma unroll
    for (int j = 0; j < 4; ++j) acc[i][j] = (f32x4){0.f, 0.f, 0.f, 0.f};
  gemm128_core(X, W, bm, bn, acc, Xs, Ws);
  const int lane = threadIdx.x & 63, wave = threadIdx.x >> 6;
  const int wm = (wave >> 1) * 64, wn = (wave & 1) * 64;
  const int r0 = (lane >> 4) * 4;
#pragma unroll
  for (int mi = 0; mi < 4; ++mi)
#pragma unroll
    for (int ni = 0; ni < 4; ++ni) {
      const int row = bm * 128 + wm + mi * 16 + r0;
      const int col = bn * 128 + wn + ni * 16 + (lane & 15);
      const float bv = bias[col];
#pragma unroll
      for (int r = 0; r < 4; ++r)
        C[(size_t)(row + r) * 1024 + col] = acc[mi][ni][r] + bv;
    }
}

// ---------------------------------------------------------------------------
// Per-chunk KV state in B-frag IMAGE layout (round-4 verified VALU version):
//   Simg flat idx = (d>>3)*512 + e*8 + (d&7)  (fp32, prefix-summed later)
// Also emits V image: vimg[bid][sg*64+e][j] = v[sg*8+j][e] (bf16).
// ---------------------------------------------------------------------------
__global__ __launch_bounds__(256)
void chunk_kv(const __hip_bfloat16* __restrict__ Kp,
              const __hip_bfloat16* __restrict__ Vp,
              float* __restrict__ kvout, float* __restrict__ zkout,
              unsigned short* __restrict__ vimg)
{
  const int bid = blockIdx.x;  // b*256 + h*16 + n
  const int n = bid & 15, h = (bid >> 4) & 15, b = bid >> 8;
  __shared__ __align__(16) __hip_bfloat16 ks[CHUNK_ * HDIM];
  __shared__ __align__(16) __hip_bfloat16 vs[CHUNK_ * HDIM];
  const size_t base = ((size_t)(b * T_LEN + n * CHUNK_)) * E_DIM + h * HDIM;
  const int t = threadIdx.x;
  for (int i = t; i < CHUNK_ * 8; i += 256) {
    int r = i >> 3, c = (i & 7) << 3;
    *(uint4*)&ks[r * HDIM + c] = *(const uint4*)(Kp + base + (size_t)r * E_DIM + c);
    *(uint4*)&vs[r * HDIM + c] = *(const uint4*)(Vp + base + (size_t)r * E_DIM + c);
  }
  __syncthreads();
  const int d0 = (t >> 4) << 2, e0 = (t & 15) << 2;
  float acc[4][4] = {{0.f}};
  float z[4] = {0.f, 0.f, 0.f, 0.f};
  for (int c = 0; c < CHUNK_; ++c) {
    float kv4[4], vv4[4];
#pragma unroll
    for (int i = 0; i < 4; ++i) kv4[i] = b2f(ks[c * HDIM + d0 + i]);
#pragma unroll
    for (int j = 0; j < 4; ++j) vv4[j] = b2f(vs[c * HDIM + e0 + j]);
#pragma unroll
    for (int i = 0; i < 4; ++i) {
      z[i] += kv4[i];
#pragma unroll
      for (int j = 0; j < 4; ++j) acc[i][j] += kv4[i] * vv4[j];
    }
  }
  float* o = kvout + (size_t)bid * (HDIM * HDIM);
  const int dg = d0 >> 3, doff = d0 & 7;
#pragma unroll
  for (int i = 0; i < 4; ++i)
#pragma unroll
    for (int j = 0; j < 4; ++j)
      o[dg * 512 + (e0 + j) * 8 + doff + i] = acc[i][j];  // image layout
  if (e0 == 0) {
#pragma unroll
    for (int i = 0; i < 4; ++i) zkout[(size_t)bid * HDIM + d0 + i] = z[i];
  }
  // V image: slot = sg*64+e, elems j -> v[sg*8+j][e]
  const unsigned short* vsu = (const unsigned short*)vs;
  unsigned short* vo = vimg + (size_t)bid * 8192;
  for (int slot = t; slot < 1024; slot += 256) {
    const int sg = slot >> 6, e = slot & 63;
    ushort4 lo, hi;
    lo.x = vsu[(sg * 8 + 0) * 64 + e]; lo.y = vsu[(sg * 8 + 1) * 64 + e];
    lo.z = vsu[(sg * 8 + 2) * 64 + e]; lo.w = vsu[(sg * 8 + 3) * 64 + e];
    hi.x = vsu[(sg * 8 + 4) * 64 + e]; hi.y = vsu[(sg * 8 + 5) * 64 + e];
    hi.z = vsu[(sg * 8 + 6) * 64 + e]; hi.w = vsu[(sg * 8 + 7) * 64 + e];
    *(ushort4*)&vo[slot * 8] = lo;
    *(ushort4*)&vo[slot * 8 + 4] = hi;
  }
}

// ---------------------------------------------------------------------------
// In-place exclusive prefix over chunks (elementwise; layout-agnostic).
// ---------------------------------------------------------------------------
__global__ __launch_bounds__(256)
void prefix_chunks(float* __restrict__ S, float* __restrict__ Z)
{
  const int bh = blockIdx.x;
  const int t = threadIdx.x;
  float run[16];
#pragma unroll
  for (int j = 0; j < 16; ++j) run[j] = 0.f;
  for (int n = 0; n < NCHUNK; ++n) {
    float* p = S + ((size_t)bh * NCHUNK + n) * (HDIM * HDIM);
#pragma unroll
    for (int j = 0; j < 16; ++j) {
      int idx = t + j * 256;
      float cur = p[idx];
      p[idx] = run[j];
      run[j] += cur;
    }
  }
  if (t < HDIM) {
    float rz = 0.f;
    for (int n = 0; n < NCHUNK; ++n) {
      float* p = Z + ((size_t)bh * NCHUNK + n) * HDIM + t;
      float cur = *p;
      *p = rz;
      rz += cur;
    }
  }
}

// ---------------------------------------------------------------------------
// Barrier-free MFMA chunk_attn (round-4 verified).
// ---------------------------------------------------------------------------
#define PW_STRIDE 136  // 272 B row stride: 2-way-free banks, 16B aligned

__global__ __launch_bounds__(256, 3)
void chunk_attn(const __hip_bfloat16* __restrict__ Qp,
                const __hip_bfloat16* __restrict__ Kp,
                const unsigned short* __restrict__ vimg,  // [bid][1024 slots][8]
                const float* __restrict__ Simg,           // [bid][4096] image fp32
                const float* __restrict__ Zp,             // [bid][64]
                __hip_bfloat16* __restrict__ Yp)
{
  __shared__ __align__(16) unsigned short VL[8192];             // 16 KB
  __shared__ __align__(16) unsigned short SL[4096];             // 8 KB
  __shared__ __align__(16) unsigned short PL[4 * 16 * PW_STRIDE];  // 17 KB

  const int bid = blockIdx.x;
  const int n = bid & 15, h = (bid >> 4) & 15, b = bid >> 8;
  const int tokbase = b * T_LEN + n * CHUNK_;
  const size_t gbase = (size_t)tokbase * E_DIM + h * HDIM;
  const int t = threadIdx.x, lane = t & 63, wv = t >> 6;
  const int lm = lane & 15, kg = lane >> 4;

  // ---- stage V image (contiguous async) ----
#pragma unroll
  for (int i = 0; i < 4; ++i) {
    const int j = wv * 4 + i;
    gld_lds16(vimg + (size_t)bid * 8192 + (size_t)(j * 64 + lane) * 8,
              (char*)VL + j * 1024);
  }
  // ---- stage S image fp32 -> bf16 (contiguous) ----
#pragma unroll
  for (int i = 0; i < 4; ++i) {
    const int idx = i * 1024 + t * 4;
    float4 s4 = *(const float4*)(Simg + (size_t)bid * 4096 + idx);
    ushort4 o;
    o.x = f2bu(s4.x); o.y = f2bu(s4.y); o.z = f2bu(s4.z); o.w = f2bu(s4.w);
    *(ushort4*)&SL[idx] = o;
  }

  const int mts[2] = { wv, 7 - wv };
  // ---- phiq A/B frags from global (layout identical for A and B) ----
  bf16x8 aq[2][2];
#pragma unroll
  for (int mi = 0; mi < 2; ++mi)
#pragma unroll
    for (int kh = 0; kh < 2; ++kh)
      aq[mi][kh] = *(const bf16x8*)(Qp + gbase +
                    (size_t)(mts[mi] * 16 + lm) * E_DIM + kh * 32 + kg * 8);
  // ---- Z broadcast-B frags (value depends only on k) ----
  bf16x8 zb[2];
#pragma unroll
  for (int kh = 0; kh < 2; ++kh) {
    float4 z0 = *(const float4*)(Zp + (size_t)bid * 64 + kh * 32 + kg * 8);
    float4 z1 = *(const float4*)(Zp + (size_t)bid * 64 + kh * 32 + kg * 8 + 4);
    zb[kh][0] = (short)f2bu(z0.x); zb[kh][1] = (short)f2bu(z0.y);
    zb[kh][2] = (short)f2bu(z0.z); zb[kh][3] = (short)f2bu(z0.w);
    zb[kh][4] = (short)f2bu(z1.x); zb[kh][5] = (short)f2bu(z1.y);
    zb[kh][6] = (short)f2bu(z1.z); zb[kh][7] = (short)f2bu(z1.w);
  }

  __syncthreads();  // the ONLY barrier: all staging (incl. async V) visible

  f32x4 accn[2][4];
  f32x4 accden[2];
#pragma unroll
  for (int mi = 0; mi < 2; ++mi) {
    accden[mi] = (f32x4){EPS_, EPS_, EPS_, EPS_};
#pragma unroll
    for (int ne = 0; ne < 4; ++ne) accn[mi][ne] = (f32x4){0.f, 0.f, 0.f, 0.f};
  }

  // ---- history: num += phiq @ S_prev ; den += phiq . Z ----
#pragma unroll
  for (int mi = 0; mi < 2; ++mi)
#pragma unroll
    for (int kh = 0; kh < 2; ++kh) {
      const bf16x8 a = aq[mi][kh];
      accden[mi] = MFMA16(a, zb[kh], accden[mi]);
#pragma unroll
      for (int ne = 0; ne < 4; ++ne) {
        bf16x8 bs = *(const bf16x8*)&SL[((kh * 4 + kg) * 64 + ne * 16 + lm) * 8];
        accn[mi][ne] = MFMA16(a, bs, accn[mi][ne]);
      }
    }

  // ---- per-wave causal part: PT tiles -> private P LDS -> PV ----
  unsigned short* Pw = PL + wv * 16 * PW_STRIDE;
  bf16x8 ones;
#pragma unroll
  for (int j = 0; j < 8; ++j) ones[j] = (short)0x3F80;

#pragma unroll
  for (int mi = 0; mi < 2; ++mi) {
    const int mt = mts[mi], m0 = mt * 16;
    // PT tiles (s-tile nt, m-cols of tile mt); same wave writes P[m][s]
    for (int nt = 0; nt <= mt; ++nt) {
      f32x4 pt = (f32x4){0.f, 0.f, 0.f, 0.f};
#pragma unroll
      for (int kh = 0; kh < 2; ++kh) {
        bf16x8 ak = *(const bf16x8*)(Kp + gbase +
                     (size_t)(nt * 16 + lm) * E_DIM + kh * 32 + kg * 8);
        pt = MFMA16(ak, aq[mi][kh], pt);
      }
      unsigned short u[4];
#pragma unroll
      for (int r = 0; r < 4; ++r) {
        float v = pt[r];
        if (nt == mt) {  // diagonal: rows s_local=kg*4+r, cols m_local=lm; keep s<=m
          v = ((kg * 4 + r) <= lm) ? v : 0.f;
        }
        u[r] = f2bu(v);
      }
      const int sidx = lm * PW_STRIDE + nt * 16 + kg * 4;
      *(unsigned*)&Pw[sidx]     = (unsigned)u[0] | ((unsigned)u[1] << 16);
      *(unsigned*)&Pw[sidx + 2] = (unsigned)u[2] | ((unsigned)u[3] << 16);
    }
    // zero-fill to 32-boundary for even mt
    if ((mt & 1) == 0 && lane < 32) {
      const int m = lane >> 1, half = lane & 1;
      *(uint4*)&Pw[m * PW_STRIDE + (mt + 1) * 16 + half * 8] = (uint4){0u, 0u, 0u, 0u};
    }
    // PV + rowsum(P)
    const int ktc = (mt + 2) >> 1;
    for (int kt = 0; kt < ktc; ++kt) {
      bf16x8 ap = *(const bf16x8*)&Pw[lm * PW_STRIDE + kt * 32 + kg * 8];
      accden[mi] = MFMA16(ap, ones, accden[mi]);
#pragma unroll
      for (int ne = 0; ne < 4; ++ne) {
        bf16x8 bv = *(const bf16x8*)&VL[((kt * 4 + kg) * 64 + ne * 16 + lm) * 8];
        accn[mi][ne] = MFMA16(ap, bv, accn[mi][ne]);
      }
    }
  }

  // ---- epilogue: y = num / den (accden rows == accn rows) ----
#pragma unroll
  for (int mi = 0; mi < 2; ++mi) {
    const int m0 = mts[mi] * 16;
    float inv[4];
#pragma unroll
    for (int r = 0; r < 4; ++r) inv[r] = 1.f / accden[mi][r];
#pragma unroll
    for (int ne = 0; ne < 4; ++ne) {
      const int col = h * HDIM + ne * 16 + lm;
#pragma unroll
      for (int r = 0; r < 4; ++r) {
        const int row = tokbase + m0 + kg * 4 + r;
        Yp[(size_t)row * E_DIM + col] = __float2bfloat16(accn[mi][ne][r] * inv[r]);
      }
    }
  }
}

// ---------------------------------------------------------------------------
extern "C" void kernel_launch(void* const* d_in, const int* in_sizes, int n_in,
                              void* d_out, int out_size, void* d_ws, size_t ws_size,
                              hipStream_t stream)
{
  const float* x  = (const float*)d_in[0];
  const float* Wq = (const float*)d_in[1];
  const float* Wk = (const float*)d_in[2];
  const float* Wv = (const float*)d_in[3];
  const float* Wp = (const float*)d_in[4];
  const float* bp = (const float*)d_in[5];
  float* out = (float*)d_out;

  const size_t MT = (size_t)BATCH * T_LEN;  // 8192 rows
  char* w = (char*)d_ws;
  __hip_bfloat16* xb  = (__hip_bfloat16*)w; w += MT * E_DIM * sizeof(__hip_bfloat16);
  __hip_bfloat16* Wqb = (__hip_bfloat16*)w; w += (size_t)E_DIM * E_DIM * sizeof(__hip_bfloat16);
  __hip_bfloat16* Wkb = (__hip_bfloat16*)w; w += (size_t)E_DIM * E_DIM * sizeof(__hip_bfloat16);
  __hip_bfloat16* Wvb = (__hip_bfloat16*)w; w += (size_t)E_DIM * E_DIM * sizeof(__hip_bfloat16);
  __hip_bfloat16* Wpb = (__hip_bfloat16*)w; w += (size_t)E_DIM * E_DIM * sizeof(__hip_bfloat16);
  __hip_bfloat16* q = (__hip_bfloat16*)w; w += MT * E_DIM * sizeof(__hip_bfloat16);
  __hip_bfloat16* k = (__hip_bfloat16*)w; w += MT * E_DIM * sizeof(__hip_bfloat16);
  __hip_bfloat16* v = (__hip_bfloat16*)w; w += MT * E_DIM * sizeof(__hip_bfloat16);
  __hip_bfloat16* y = (__hip_bfloat16*)w; w += MT * E_DIM * sizeof(__hip_bfloat16);
  float* S = (float*)w; w += (size_t)BATCH * HEADS * NCHUNK * HDIM * HDIM * sizeof(float);
  float* Z = (float*)w; w += (size_t)BATCH * HEADS * NCHUNK * HDIM * sizeof(float);
  // V image reuses xb (dead after gemm_qkv; chunk_kv runs strictly after)
  unsigned short* vimg = (unsigned short*)xb;

  cast5<<<8192 + 4096, 256, 0, stream>>>(x, Wq, Wk, Wv, Wp, xb, Wqb, Wkb, Wvb, Wpb);
  gemm_qkv_v3<<<dim3(32, 12), 512, 0, stream>>>(xb, Wqb, Wkb, Wvb, q, k, v);
  chunk_kv<<<BATCH * HEADS * NCHUNK, 256, 0, stream>>>(k, v, S, Z, vimg);
  prefix_chunks<<<BATCH * HEADS, 256, 0, stream>>>(S, Z);
  chunk_attn<<<BATCH * HEADS * NCHUNK, 256, 0, stream>>>(q, k, vimg, S, Z, y);
  gemm_out<<<dim3(MT / 128, 8), 256, 0, stream>>>(y, Wpb, bp, out);
}

// Round 4
// 233.961 us; speedup vs baseline: 1.0736x; 1.0736x over previous
//
#include <hip/hip_runtime.h>
#include <hip/hip_bf16.h>
#include <stdint.h>

#define T_LEN  2048
#define E_DIM  1024
#define BATCH  4
#define HEADS  16
#define HDIM   64
#define CHUNK_ 128
#define NCHUNK 16
#define EPS_   1e-6f

typedef __attribute__((ext_vector_type(8))) short bf16x8;
typedef __attribute__((ext_vector_type(4))) float f32x4;

__device__ __forceinline__ float b2f(__hip_bfloat16 h) { return __bfloat162float(h); }
__device__ __forceinline__ float bu2f(unsigned short u) {
  return __uint_as_float((unsigned)u << 16);
}
__device__ __forceinline__ unsigned short f2bu(float f) {
  __hip_bfloat16 h = __float2bfloat16(f);
  return *(unsigned short*)&h;
}
// async global->LDS, 16B per lane; LDS dest = base + lane*16 (wave-uniform base)
__device__ __forceinline__ void gld_lds16(const void* g, void* l) {
  __builtin_amdgcn_global_load_lds((const __attribute__((address_space(1))) void*)g,
                                   (__attribute__((address_space(3))) void*)l,
                                   16, 0, 0);
}

#define MFMA16(a, b, c) __builtin_amdgcn_mfma_f32_16x16x32_bf16((a), (b), (c), 0, 0, 0)

// ---------------------------------------------------------------------------
// fp32 -> bf16 cast for x (8192x1024) and four 1024x1024 weights.
// ---------------------------------------------------------------------------
__global__ __launch_bounds__(256)
void cast5(const float* __restrict__ x,  const float* __restrict__ w0,
           const float* __restrict__ w1, const float* __restrict__ w2,
           const float* __restrict__ w3,
           __hip_bfloat16* __restrict__ xb,  __hip_bfloat16* __restrict__ w0b,
           __hip_bfloat16* __restrict__ w1b, __hip_bfloat16* __restrict__ w2b,
           __hip_bfloat16* __restrict__ w3b)
{
  const int b = blockIdx.x;
  const float* s;
  __hip_bfloat16* d;
  size_t off;
  if (b < 8192) { s = x; d = xb; off = (size_t)b * 1024; }
  else {
    const int i = (b - 8192) >> 10;
    const int r = (b - 8192) & 1023;
    s = (i == 0) ? w0 : (i == 1) ? w1 : (i == 2) ? w2 : w3;
    d = (i == 0) ? w0b : (i == 1) ? w1b : (i == 2) ? w2b : w3b;
    off = (size_t)r * 1024;
  }
  const int t = threadIdx.x;
  float4 v = *(const float4*)(s + off + (size_t)t * 4);
  ushort4 o;
  o.x = f2bu(v.x); o.y = f2bu(v.y); o.z = f2bu(v.z); o.w = f2bu(v.w);
  *(ushort4*)((unsigned short*)d + off + (size_t)t * 4) = o;
}

// ---------------------------------------------------------------------------
// 128x128 GEMM core (m97 structure) — still used by gemm_out.
// ---------------------------------------------------------------------------
__device__ __forceinline__ void gemm128_core(
    const __hip_bfloat16* __restrict__ X,
    const __hip_bfloat16* __restrict__ W,
    int bm, int bn, f32x4 acc[4][4],
    __hip_bfloat16* Xs, __hip_bfloat16* Ws)
{
  const int t = threadIdx.x, lane = t & 63, wave = t >> 6;
  const int wm = (wave >> 1) * 64, wn = (wave & 1) * 64;
  for (int k0 = 0; k0 < 1024; k0 += 32) {
    if (k0) __syncthreads();
#pragma unroll
    for (int i = 0; i < 2; ++i) {
      const int j = wave * 2 + i;
      const int m = j * 16 + (lane >> 2);
      const int kg = lane & 3;
      gld_lds16(X + (size_t)(bm * 128 + m) * 1024 + k0 + kg * 8, (char*)Xs + j * 1024);
      gld_lds16(W + (size_t)(bn * 128 + m) * 1024 + k0 + kg * 8, (char*)Ws + j * 1024);
    }
    __syncthreads();
    bf16x8 a[4], b[4];
#pragma unroll
    for (int i = 0; i < 4; ++i) {
      a[i] = *(const bf16x8*)&Xs[((wm + i * 16 + (lane & 15)) * 4 + (lane >> 4)) * 8];
      b[i] = *(const bf16x8*)&Ws[((wn + i * 16 + (lane & 15)) * 4 + (lane >> 4)) * 8];
    }
#pragma unroll
    for (int i = 0; i < 4; ++i)
#pragma unroll
      for (int jn = 0; jn < 4; ++jn)
        acc[i][jn] = MFMA16(a[i], b[jn], acc[i][jn]);
  }
}

// ---------------------------------------------------------------------------
// Fused q/k/v projection v2 (r2-verified, 63us) — 128x256 tile, BK=64,
// 16 K-steps. Grid (64, 12) = 768 blocks = exactly 3 rounds at 1 block/CU.
// 512 threads = 8 waves (2M x 4N); per-wave output 64x64 (acc[4][4]).
// LDS: 3-deep circular buffer x (A 128x64 + B 256x64) bf16 = 144 KiB.
// ONE barrier + ONE counted vmcnt(6) per K-step (T4: never drain to 0 in
// the main loop — v3's vmcnt(0)/step was the 63->96us regression).
// ---------------------------------------------------------------------------
__global__ __launch_bounds__(512, 1)
void gemm_qkv_v2(const __hip_bfloat16* __restrict__ X,
                 const __hip_bfloat16* __restrict__ Wq,
                 const __hip_bfloat16* __restrict__ Wk,
                 const __hip_bfloat16* __restrict__ Wv,
                 __hip_bfloat16* __restrict__ qo,
                 __hip_bfloat16* __restrict__ ko,
                 __hip_bfloat16* __restrict__ vo)
{
  __shared__ __align__(16) unsigned short As[3][8192];    // 3 x 16 KiB
  __shared__ __align__(16) unsigned short Bs[3][16384];   // 3 x 32 KiB

  const int bm = blockIdx.x;            // 0..63 (M tiles of 128)
  const int byy = blockIdx.y;           // 0..11
  const int which = byy >> 2, bn = byy & 3;
  const __hip_bfloat16* Wsel = (which == 0) ? Wq : (which == 1) ? Wk : Wv;
  __hip_bfloat16* Cc = (which == 0) ? qo : (which == 1) ? ko : vo;
  const bool elu = (which < 2);

  const int t = threadIdx.x, lane = t & 63, wv = t >> 6;
  const int wm = (wv >> 2) * 64;        // 0 / 64
  const int wn = (wv & 3) * 64;         // 0 / 64 / 128 / 192

  const __hip_bfloat16* Xp = X + (size_t)(bm * 128) * 1024;
  const __hip_bfloat16* Wp = Wsel + (size_t)(bn * 256) * 1024;

  // ds_read address pieces (bytes within one buffer):
  // addr = rowbase*128 + (l&15)*128 + (((ks*4)+(l>>4)) ^ (l&7))*16
  const int lo    = (lane & 15) * 128;
  const int lohi0 = lo + (((lane >> 4)    ) ^ (lane & 7)) * 16;
  const int lohi1 = lo + (((lane >> 4) | 4) ^ (lane & 7)) * 16;
  // stage source pieces: row = row0 + (l>>3), granule cg = (l&7)^(l>>3)
  const int srow = lane >> 3;
  const int scg  = (lane & 7) ^ (lane >> 3);

  auto stA = [&](int buf, int k0) {     // A rows 0..127, 2 chunks/wave
#pragma unroll
    for (int ci = 0; ci < 2; ++ci) {
      const int row0 = (wv * 2 + ci) * 8;
      gld_lds16(Xp + (size_t)(row0 + srow) * 1024 + k0 + scg * 8,
                (char*)&As[buf][0] + row0 * 128);
    }
  };
  auto stB0 = [&](int buf, int k0) {    // B rows 0..127
#pragma unroll
    for (int ci = 0; ci < 2; ++ci) {
      const int row0 = (wv * 2 + ci) * 8;
      gld_lds16(Wp + (size_t)(row0 + srow) * 1024 + k0 + scg * 8,
                (char*)&Bs[buf][0] + row0 * 128);
    }
  };
  auto stB1 = [&](int buf, int k0) {    // B rows 128..255
#pragma unroll
    for (int ci = 0; ci < 2; ++ci) {
      const int row0 = 128 + (wv * 2 + ci) * 8;
      gld_lds16(Wp + (size_t)(row0 + srow) * 1024 + k0 + scg * 8,
                (char*)&Bs[buf][0] + row0 * 128);
    }
  };
  auto rdA = [&](int buf, int half, bf16x8 (&d)[2][2]) {
#pragma unroll
    for (int m = 0; m < 2; ++m) {
      const int rb = wm + half * 32 + m * 16;
      d[m][0] = *(const bf16x8*)((const char*)&As[buf][0] + rb * 128 + lohi0);
      d[m][1] = *(const bf16x8*)((const char*)&As[buf][0] + rb * 128 + lohi1);
    }
  };
  auto rdB = [&](int buf, int half, bf16x8 (&d)[2][2]) {
#pragma unroll
    for (int n = 0; n < 2; ++n) {
      const int rb = wn + half * 32 + n * 16;
      d[n][0] = *(const bf16x8*)((const char*)&Bs[buf][0] + rb * 128 + lohi0);
      d[n][1] = *(const bf16x8*)((const char*)&Bs[buf][0] + rb * 128 + lohi1);
    }
  };

  f32x4 acc[4][4];
#pragma unroll
  for (int m = 0; m < 4; ++m)
#pragma unroll
    for (int n = 0; n < 4; ++n) acc[m][n] = (f32x4){0.f, 0.f, 0.f, 0.f};

  // two register frag sets (ping-pong; all indices compile-time)
  bf16x8 Aa01[2][2], Ab01[2][2], Aa23[2][2], Ab23[2][2];
  bf16x8 Ba01[2][2], Bb01[2][2], Ba23[2][2], Bb23[2][2];

  // ---- prologue: stage steps 0 and 1; wait step 0 (6 newest = step 1) ----
  stA(0, 0);  stB0(0, 0);  stB1(0, 0);
  stA(1, 64); stB0(1, 64); stB1(1, 64);
  asm volatile("s_waitcnt vmcnt(6)" ::: "memory");
  __builtin_amdgcn_s_barrier();
  __builtin_amdgcn_sched_barrier(0);
  rdA(0, 0, Aa01); rdB(0, 0, Ab01); rdA(0, 1, Aa23); rdB(0, 1, Ab23);

  auto qstep = [&](int j, int c,
                   bf16x8 (&ca01)[2][2], bf16x8 (&cb01)[2][2],
                   bf16x8 (&ca23)[2][2], bf16x8 (&cb23)[2][2],
                   bf16x8 (&na01)[2][2], bf16x8 (&nb01)[2][2],
                   bf16x8 (&na23)[2][2], bf16x8 (&nb23)[2][2]) {
    const int stg  = (c + 2 >= 3) ? c - 1 : c + 2;   // (c+2)%3
    const int nbuf = (c + 1 >= 3) ? 0 : c + 1;       // (c+1)%3
    const int k0n  = (j + 2) * 64;
    const bool dost = (j < 14);

    // Q0: a01 x b01
    __builtin_amdgcn_s_setprio(1);
#pragma unroll
    for (int m = 0; m < 2; ++m)
#pragma unroll
      for (int n = 0; n < 2; ++n) {
        acc[m][n] = MFMA16(ca01[m][0], cb01[n][0], acc[m][n]);
        acc[m][n] = MFMA16(ca01[m][1], cb01[n][1], acc[m][n]);
      }
    __builtin_amdgcn_s_setprio(0);
    if (dost) stA(stg, k0n);

    // Q1: a01 x b23
    __builtin_amdgcn_s_setprio(1);
#pragma unroll
    for (int m = 0; m < 2; ++m)
#pragma unroll
      for (int n = 0; n < 2; ++n) {
        acc[m][2 + n] = MFMA16(ca01[m][0], cb23[n][0], acc[m][2 + n]);
        acc[m][2 + n] = MFMA16(ca01[m][1], cb23[n][1], acc[m][2 + n]);
      }
    __builtin_amdgcn_s_setprio(0);
    if (dost) stB0(stg, k0n);

    // Q2: a23 x b01
    __builtin_amdgcn_s_setprio(1);
#pragma unroll
    for (int m = 0; m < 2; ++m)
#pragma unroll
      for (int n = 0; n < 2; ++n) {
        acc[2 + m][n] = MFMA16(ca23[m][0], cb01[n][0], acc[2 + m][n]);
        acc[2 + m][n] = MFMA16(ca23[m][1], cb01[n][1], acc[2 + m][n]);
      }
    __builtin_amdgcn_s_setprio(0);
    if (dost) stB1(stg, k0n);

    // step j+1's staging (issued during step j-1) must be globally visible
    if (j == 14) asm volatile("s_waitcnt vmcnt(0)" ::: "memory");
    else         asm volatile("s_waitcnt vmcnt(6)" ::: "memory");
    __builtin_amdgcn_s_barrier();
    __builtin_amdgcn_sched_barrier(0);

    // reads for step j+1 (first half), overlapped by Q3's register-only MFMAs
    rdA(nbuf, 0, na01); rdB(nbuf, 0, nb01);

    // Q3: a23 x b23
    __builtin_amdgcn_s_setprio(1);
#pragma unroll
    for (int m = 0; m < 2; ++m)
#pragma unroll
      for (int n = 0; n < 2; ++n) {
        acc[2 + m][2 + n] = MFMA16(ca23[m][0], cb23[n][0], acc[2 + m][2 + n]);
        acc[2 + m][2 + n] = MFMA16(ca23[m][1], cb23[n][1], acc[2 + m][2 + n]);
      }
    __builtin_amdgcn_s_setprio(0);

    rdA(nbuf, 1, na23); rdB(nbuf, 1, nb23);
  };

  int c = 0;
#pragma unroll 1
  for (int jj = 0; jj < 8; ++jj) {
    qstep(2 * jj, c, Aa01, Ab01, Aa23, Ab23, Ba01, Bb01, Ba23, Bb23);
    c = (c == 2) ? 0 : c + 1;
    qstep(2 * jj + 1, c, Ba01, Bb01, Ba23, Bb23, Aa01, Ab01, Aa23, Ab23);
    c = (c == 2) ? 0 : c + 1;
  }

  // ---- epilogue: optional elu(x)+1 and bf16 store ----
  const int lm = lane & 15;
  const int r0 = (lane >> 4) * 4;
#pragma unroll
  for (int m = 0; m < 4; ++m) {
    const int row = bm * 128 + wm + m * 16 + r0;
#pragma unroll
    for (int n = 0; n < 4; ++n) {
      const int col = bn * 256 + wn + n * 16 + lm;
#pragma unroll
      for (int r = 0; r < 4; ++r) {
        float vv = acc[m][n][r];
        if (elu) vv = (vv > 0.f) ? (vv + 1.f) : __expf(vv);
        Cc[(size_t)(row + r) * 1024 + col] = __float2bfloat16(vv);
      }
    }
  }
}

// output projection: fp32 out + bias; grid (64, 8)
__global__ __launch_bounds__(256, 2)
void gemm_out(const __hip_bfloat16* __restrict__ X,
              const __hip_bfloat16* __restrict__ W,
              const float* __restrict__ bias,
              float* __restrict__ C)
{
  __shared__ __align__(16) __hip_bfloat16 Xs[128 * 32];
  __shared__ __align__(16) __hip_bfloat16 Ws[128 * 32];
  const int bm = blockIdx.x, bn = blockIdx.y;
  f32x4 acc[4][4];
#pragma unroll
  for (int i = 0; i < 4; ++i)
#pragma unroll
    for (int j = 0; j < 4; ++j) acc[i][j] = (f32x4){0.f, 0.f, 0.f, 0.f};
  gemm128_core(X, W, bm, bn, acc, Xs, Ws);
  const int lane = threadIdx.x & 63, wave = threadIdx.x >> 6;
  const int wm = (wave >> 1) * 64, wn = (wave & 1) * 64;
  const int r0 = (lane >> 4) * 4;
#pragma unroll
  for (int mi = 0; mi < 4; ++mi)
#pragma unroll
    for (int ni = 0; ni < 4; ++ni) {
      const int row = bm * 128 + wm + mi * 16 + r0;
      const int col = bn * 128 + wn + ni * 16 + (lane & 15);
      const float bv = bias[col];
#pragma unroll
      for (int r = 0; r < 4; ++r)
        C[(size_t)(row + r) * 1024 + col] = acc[mi][ni][r] + bv;
    }
}

// ---------------------------------------------------------------------------
// Per-chunk KV state in B-frag IMAGE layout (round-4 verified VALU version):
//   Simg flat idx = (d>>3)*512 + e*8 + (d&7)  (fp32, prefix-summed later)
// Also emits V image: vimg[bid][sg*64+e][j] = v[sg*8+j][e] (bf16).
// Inner loop: explicit ushort4 (b64) LDS reads + shift-convert (G13).
// ---------------------------------------------------------------------------
__global__ __launch_bounds__(256)
void chunk_kv(const __hip_bfloat16* __restrict__ Kp,
              const __hip_bfloat16* __restrict__ Vp,
              float* __restrict__ kvout, float* __restrict__ zkout,
              unsigned short* __restrict__ vimg)
{
  const int bid = blockIdx.x;  // b*256 + h*16 + n
  const int n = bid & 15, h = (bid >> 4) & 15, b = bid >> 8;
  __shared__ __align__(16) __hip_bfloat16 ks[CHUNK_ * HDIM];
  __shared__ __align__(16) __hip_bfloat16 vs[CHUNK_ * HDIM];
  const size_t base = ((size_t)(b * T_LEN + n * CHUNK_)) * E_DIM + h * HDIM;
  const int t = threadIdx.x;
  for (int i = t; i < CHUNK_ * 8; i += 256) {
    int r = i >> 3, c = (i & 7) << 3;
    *(uint4*)&ks[r * HDIM + c] = *(const uint4*)(Kp + base + (size_t)r * E_DIM + c);
    *(uint4*)&vs[r * HDIM + c] = *(const uint4*)(Vp + base + (size_t)r * E_DIM + c);
  }
  __syncthreads();
  const int d0 = (t >> 4) << 2, e0 = (t & 15) << 2;
  const unsigned short* ksu = (const unsigned short*)ks;
  const unsigned short* vsu0 = (const unsigned short*)vs;
  float acc[4][4] = {{0.f}};
  float z[4] = {0.f, 0.f, 0.f, 0.f};
  for (int c = 0; c < CHUNK_; ++c) {
    ushort4 kq = *(const ushort4*)(ksu + c * HDIM + d0);
    ushort4 vq = *(const ushort4*)(vsu0 + c * HDIM + e0);
    float kv4[4], vv4[4];
    kv4[0] = bu2f(kq.x); kv4[1] = bu2f(kq.y); kv4[2] = bu2f(kq.z); kv4[3] = bu2f(kq.w);
    vv4[0] = bu2f(vq.x); vv4[1] = bu2f(vq.y); vv4[2] = bu2f(vq.z); vv4[3] = bu2f(vq.w);
#pragma unroll
    for (int i = 0; i < 4; ++i) {
      z[i] += kv4[i];
#pragma unroll
      for (int j = 0; j < 4; ++j) acc[i][j] += kv4[i] * vv4[j];
    }
  }
  float* o = kvout + (size_t)bid * (HDIM * HDIM);
  const int dg = d0 >> 3, doff = d0 & 7;
#pragma unroll
  for (int i = 0; i < 4; ++i)
#pragma unroll
    for (int j = 0; j < 4; ++j)
      o[dg * 512 + (e0 + j) * 8 + doff + i] = acc[i][j];  // image layout
  if (e0 == 0) {
#pragma unroll
    for (int i = 0; i < 4; ++i) zkout[(size_t)bid * HDIM + d0 + i] = z[i];
  }
  // V image: slot = sg*64+e, elems j -> v[sg*8+j][e]
  const unsigned short* vsu = (const unsigned short*)vs;
  unsigned short* vo = vimg + (size_t)bid * 8192;
  for (int slot = t; slot < 1024; slot += 256) {
    const int sg = slot >> 6, e = slot & 63;
    ushort4 lo, hi;
    lo.x = vsu[(sg * 8 + 0) * 64 + e]; lo.y = vsu[(sg * 8 + 1) * 64 + e];
    lo.z = vsu[(sg * 8 + 2) * 64 + e]; lo.w = vsu[(sg * 8 + 3) * 64 + e];
    hi.x = vsu[(sg * 8 + 4) * 64 + e]; hi.y = vsu[(sg * 8 + 5) * 64 + e];
    hi.z = vsu[(sg * 8 + 6) * 64 + e]; hi.w = vsu[(sg * 8 + 7) * 64 + e];
    *(ushort4*)&vo[slot * 8] = lo;
    *(ushort4*)&vo[slot * 8 + 4] = hi;
  }
}

// ---------------------------------------------------------------------------
// Exclusive prefix over chunks, latency-optimal: all 16 chunk values
// prefetched in parallel (independent addresses), register prefix, 16
// independent stores. Grid 256 blocks (bh 64 x seg 4); was 64 blocks with a
// 16-deep serial load->store->load chain (~16 global round-trips).
// ---------------------------------------------------------------------------
__global__ __launch_bounds__(256)
void prefix_chunks(float* __restrict__ S, float* __restrict__ Z)
{
  const int bh = blockIdx.x >> 2, seg = blockIdx.x & 3;
  const int t = threadIdx.x;
  float* base = S + (size_t)bh * NCHUNK * (HDIM * HDIM) + seg * 1024 + t * 4;
  float4 v[NCHUNK];
#pragma unroll
  for (int n = 0; n < NCHUNK; ++n)
    v[n] = *(const float4*)(base + (size_t)n * (HDIM * HDIM));
  float4 run = {0.f, 0.f, 0.f, 0.f};
#pragma unroll
  for (int n = 0; n < NCHUNK; ++n) {
    *(float4*)(base + (size_t)n * (HDIM * HDIM)) = run;
    run.x += v[n].x; run.y += v[n].y; run.z += v[n].z; run.w += v[n].w;
  }
  if (seg == 0 && t < 16) {
    float* zb = Z + (size_t)bh * NCHUNK * HDIM + t * 4;
    float4 zv[NCHUNK];
#pragma unroll
    for (int n = 0; n < NCHUNK; ++n) zv[n] = *(const float4*)(zb + n * HDIM);
    float4 zr = {0.f, 0.f, 0.f, 0.f};
#pragma unroll
    for (int n = 0; n < NCHUNK; ++n) {
      *(float4*)(zb + n * HDIM) = zr;
      zr.x += zv[n].x; zr.y += zv[n].y; zr.z += zv[n].z; zr.w += zv[n].w;
    }
  }
}

// ---------------------------------------------------------------------------
// Barrier-free MFMA chunk_attn (round-4 verified).
// ---------------------------------------------------------------------------
#define PW_STRIDE 136  // 272 B row stride: 2-way-free banks, 16B aligned

__global__ __launch_bounds__(256, 3)
void chunk_attn(const __hip_bfloat16* __restrict__ Qp,
                const __hip_bfloat16* __restrict__ Kp,
                const unsigned short* __restrict__ vimg,  // [bid][1024 slots][8]
                const float* __restrict__ Simg,           // [bid][4096] image fp32
                const float* __restrict__ Zp,             // [bid][64]
                __hip_bfloat16* __restrict__ Yp)
{
  __shared__ __align__(16) unsigned short VL[8192];             // 16 KB
  __shared__ __align__(16) unsigned short SL[4096];             // 8 KB
  __shared__ __align__(16) unsigned short PL[4 * 16 * PW_STRIDE];  // 17 KB

  const int bid = blockIdx.x;
  const int n = bid & 15, h = (bid >> 4) & 15, b = bid >> 8;
  const int tokbase = b * T_LEN + n * CHUNK_;
  const size_t gbase = (size_t)tokbase * E_DIM + h * HDIM;
  const int t = threadIdx.x, lane = t & 63, wv = t >> 6;
  const int lm = lane & 15, kg = lane >> 4;

  // ---- stage V image (contiguous async) ----
#pragma unroll
  for (int i = 0; i < 4; ++i) {
    const int j = wv * 4 + i;
    gld_lds16(vimg + (size_t)bid * 8192 + (size_t)(j * 64 + lane) * 8,
              (char*)VL + j * 1024);
  }
  // ---- stage S image fp32 -> bf16 (contiguous) ----
#pragma unroll
  for (int i = 0; i < 4; ++i) {
    const int idx = i * 1024 + t * 4;
    float4 s4 = *(const float4*)(Simg + (size_t)bid * 4096 + idx);
    ushort4 o;
    o.x = f2bu(s4.x); o.y = f2bu(s4.y); o.z = f2bu(s4.z); o.w = f2bu(s4.w);
    *(ushort4*)&SL[idx] = o;
  }

  const int mts[2] = { wv, 7 - wv };
  // ---- phiq A/B frags from global (layout identical for A and B) ----
  bf16x8 aq[2][2];
#pragma unroll
  for (int mi = 0; mi < 2; ++mi)
#pragma unroll
    for (int kh = 0; kh < 2; ++kh)
      aq[mi][kh] = *(const bf16x8*)(Qp + gbase +
                    (size_t)(mts[mi] * 16 + lm) * E_DIM + kh * 32 + kg * 8);
  // ---- Z broadcast-B frags (value depends only on k) ----
  bf16x8 zb[2];
#pragma unroll
  for (int kh = 0; kh < 2; ++kh) {
    float4 z0 = *(const float4*)(Zp + (size_t)bid * 64 + kh * 32 + kg * 8);
    float4 z1 = *(const float4*)(Zp + (size_t)bid * 64 + kh * 32 + kg * 8 + 4);
    zb[kh][0] = (short)f2bu(z0.x); zb[kh][1] = (short)f2bu(z0.y);
    zb[kh][2] = (short)f2bu(z0.z); zb[kh][3] = (short)f2bu(z0.w);
    zb[kh][4] = (short)f2bu(z1.x); zb[kh][5] = (short)f2bu(z1.y);
    zb[kh][6] = (short)f2bu(z1.z); zb[kh][7] = (short)f2bu(z1.w);
  }

  __syncthreads();  // the ONLY barrier: all staging (incl. async V) visible

  f32x4 accn[2][4];
  f32x4 accden[2];
#pragma unroll
  for (int mi = 0; mi < 2; ++mi) {
    accden[mi] = (f32x4){EPS_, EPS_, EPS_, EPS_};
#pragma unroll
    for (int ne = 0; ne < 4; ++ne) accn[mi][ne] = (f32x4){0.f, 0.f, 0.f, 0.f};
  }

  // ---- history: num += phiq @ S_prev ; den += phiq . Z ----
#pragma unroll
  for (int mi = 0; mi < 2; ++mi)
#pragma unroll
    for (int kh = 0; kh < 2; ++kh) {
      const bf16x8 a = aq[mi][kh];
      accden[mi] = MFMA16(a, zb[kh], accden[mi]);
#pragma unroll
      for (int ne = 0; ne < 4; ++ne) {
        bf16x8 bs = *(const bf16x8*)&SL[((kh * 4 + kg) * 64 + ne * 16 + lm) * 8];
        accn[mi][ne] = MFMA16(a, bs, accn[mi][ne]);
      }
    }

  // ---- per-wave causal part: PT tiles -> private P LDS -> PV ----
  unsigned short* Pw = PL + wv * 16 * PW_STRIDE;
  bf16x8 ones;
#pragma unroll
  for (int j = 0; j < 8; ++j) ones[j] = (short)0x3F80;

#pragma unroll
  for (int mi = 0; mi < 2; ++mi) {
    const int mt = mts[mi], m0 = mt * 16;
    // PT tiles (s-tile nt, m-cols of tile mt); same wave writes P[m][s]
    for (int nt = 0; nt <= mt; ++nt) {
      f32x4 pt = (f32x4){0.f, 0.f, 0.f, 0.f};
#pragma unroll
      for (int kh = 0; kh < 2; ++kh) {
        bf16x8 ak = *(const bf16x8*)(Kp + gbase +
                     (size_t)(nt * 16 + lm) * E_DIM + kh * 32 + kg * 8);
        pt = MFMA16(ak, aq[mi][kh], pt);
      }
      unsigned short u[4];
#pragma unroll
      for (int r = 0; r < 4; ++r) {
        float v = pt[r];
        if (nt == mt) {  // diagonal: rows s_local=kg*4+r, cols m_local=lm; keep s<=m
          v = ((kg * 4 + r) <= lm) ? v : 0.f;
        }
        u[r] = f2bu(v);
      }
      const int sidx = lm * PW_STRIDE + nt * 16 + kg * 4;
      *(unsigned*)&Pw[sidx]     = (unsigned)u[0] | ((unsigned)u[1] << 16);
      *(unsigned*)&Pw[sidx + 2] = (unsigned)u[2] | ((unsigned)u[3] << 16);
    }
    // zero-fill to 32-boundary for even mt
    if ((mt & 1) == 0 && lane < 32) {
      const int m = lane >> 1, half = lane & 1;
      *(uint4*)&Pw[m * PW_STRIDE + (mt + 1) * 16 + half * 8] = (uint4){0u, 0u, 0u, 0u};
    }
    // PV + rowsum(P)
    const int ktc = (mt + 2) >> 1;
    for (int kt = 0; kt < ktc; ++kt) {
      bf16x8 ap = *(const bf16x8*)&Pw[lm * PW_STRIDE + kt * 32 + kg * 8];
      accden[mi] = MFMA16(ap, ones, accden[mi]);
#pragma unroll
      for (int ne = 0; ne < 4; ++ne) {
        bf16x8 bv = *(const bf16x8*)&VL[((kt * 4 + kg) * 64 + ne * 16 + lm) * 8];
        accn[mi][ne] = MFMA16(ap, bv, accn[mi][ne]);
      }
    }
  }

  // ---- epilogue: y = num / den (accden rows == accn rows) ----
#pragma unroll
  for (int mi = 0; mi < 2; ++mi) {
    const int m0 = mts[mi] * 16;
    float inv[4];
#pragma unroll
    for (int r = 0; r < 4; ++r) inv[r] = 1.f / accden[mi][r];
#pragma unroll
    for (int ne = 0; ne < 4; ++ne) {
      const int col = h * HDIM + ne * 16 + lm;
#pragma unroll
      for (int r = 0; r < 4; ++r) {
        const int row = tokbase + m0 + kg * 4 + r;
        Yp[(size_t)row * E_DIM + col] = __float2bfloat16(accn[mi][ne][r] * inv[r]);
      }
    }
  }
}

// ---------------------------------------------------------------------------
extern "C" void kernel_launch(void* const* d_in, const int* in_sizes, int n_in,
                              void* d_out, int out_size, void* d_ws, size_t ws_size,
                              hipStream_t stream)
{
  const float* x  = (const float*)d_in[0];
  const float* Wq = (const float*)d_in[1];
  const float* Wk = (const float*)d_in[2];
  const float* Wv = (const float*)d_in[3];
  const float* Wp = (const float*)d_in[4];
  const float* bp = (const float*)d_in[5];
  float* out = (float*)d_out;

  const size_t MT = (size_t)BATCH * T_LEN;  // 8192 rows
  char* w = (char*)d_ws;
  __hip_bfloat16* xb  = (__hip_bfloat16*)w; w += MT * E_DIM * sizeof(__hip_bfloat16);
  __hip_bfloat16* Wqb = (__hip_bfloat16*)w; w += (size_t)E_DIM * E_DIM * sizeof(__hip_bfloat16);
  __hip_bfloat16* Wkb = (__hip_bfloat16*)w; w += (size_t)E_DIM * E_DIM * sizeof(__hip_bfloat16);
  __hip_bfloat16* Wvb = (__hip_bfloat16*)w; w += (size_t)E_DIM * E_DIM * sizeof(__hip_bfloat16);
  __hip_bfloat16* Wpb = (__hip_bfloat16*)w; w += (size_t)E_DIM * E_DIM * sizeof(__hip_bfloat16);
  __hip_bfloat16* q = (__hip_bfloat16*)w; w += MT * E_DIM * sizeof(__hip_bfloat16);
  __hip_bfloat16* k = (__hip_bfloat16*)w; w += MT * E_DIM * sizeof(__hip_bfloat16);
  __hip_bfloat16* v = (__hip_bfloat16*)w; w += MT * E_DIM * sizeof(__hip_bfloat16);
  __hip_bfloat16* y = (__hip_bfloat16*)w; w += MT * E_DIM * sizeof(__hip_bfloat16);
  float* S = (float*)w; w += (size_t)BATCH * HEADS * NCHUNK * HDIM * HDIM * sizeof(float);
  float* Z = (float*)w; w += (size_t)BATCH * HEADS * NCHUNK * HDIM * sizeof(float);
  // V image reuses xb (dead after gemm_qkv; chunk_kv runs strictly after)
  unsigned short* vimg = (unsigned short*)xb;

  cast5<<<8192 + 4096, 256, 0, stream>>>(x, Wq, Wk, Wv, Wp, xb, Wqb, Wkb, Wvb, Wpb);
  gemm_qkv_v2<<<dim3(64, 12), 512, 0, stream>>>(xb, Wqb, Wkb, Wvb, q, k, v);
  chunk_kv<<<BATCH * HEADS * NCHUNK, 256, 0, stream>>>(k, v, S, Z, vimg);
  prefix_chunks<<<BATCH * HEADS * 4, 256, 0, stream>>>(S, Z);
  chunk_attn<<<BATCH * HEADS * NCHUNK, 256, 0, stream>>>(q, k, vimg, S, Z, y);
  gemm_out<<<dim3(MT / 128, 8), 256, 0, stream>>>(y, Wpb, bp, out);
}